// Round 3
// baseline (365.901 us; speedup 1.0000x reference)
//
#include <hip/hip_runtime.h>

// Problem constants
#define NPOS 32768          // B*H*W = 32*32*32
#define DDIM 256
#define KCODE 1024
#define HW 1024             // H*W
#define BSTRIDE (256*1024)  // D*H*W per batch element
#define OUT0_SIZE 8388608   // B*D*H*W
#define OUT1_SIZE 32768

// ws layout (4-byte units):
//  [0 .. 262143]        ET  : transposed codebook [d][k]   (float)
//  [262144 .. 294911]   zn  : ||z_n||^2, numpy-pairwise f32 (float, 32768)
//  [294912 .. 295935]   en  : ||e_k||^2, numpy-pairwise f32 (float, 1024)
//  [295936 .. 328703]   idx : argmin index per position     (int)
#define WS_ET   0
#define WS_ZN   262144
#define WS_EN   294912
#define WS_IDX  295936

// ---------------------------------------------------------------------------
// numpy pairwise_sum emulation for 128 squared values accessed v(i), i=0..127:
//   r[j] = v(j); for i=8..120 step 8: r[j] += v(i+j);
//   res = ((r0+r1)+(r2+r3)) + ((r4+r5)+(r6+r7))
// All ops via __fadd_rn/__fmul_rn: IEEE f32 RTE, no contraction -> bitwise
// identical to numpy CPU f32.

// K1a: zn[n] for all positions. zf row n reads z[b*BSTRIDE + d*HW + hw].
__global__ void vq_zn(const float* __restrict__ z, float* __restrict__ zn) {
    int n = blockIdx.x * 256 + threadIdx.x;
    int b = n >> 10, hw = n & 1023;
    const float* zp = z + (size_t)b * BSTRIDE + hw;
    float half_s[2];
    #pragma unroll
    for (int h = 0; h < 2; ++h) {
        const float* p = zp + (size_t)(h * 128) * HW;
        float r[8];
        #pragma unroll
        for (int j = 0; j < 8; ++j) {
            float v = p[(size_t)j * HW];
            r[j] = __fmul_rn(v, v);
        }
        #pragma unroll
        for (int i = 8; i < 128; i += 8) {
            #pragma unroll
            for (int j = 0; j < 8; ++j) {
                float v = p[(size_t)(i + j) * HW];
                r[j] = __fadd_rn(r[j], __fmul_rn(v, v));
            }
        }
        half_s[h] = __fadd_rn(
            __fadd_rn(__fadd_rn(r[0], r[1]), __fadd_rn(r[2], r[3])),
            __fadd_rn(__fadd_rn(r[4], r[5]), __fadd_rn(r[6], r[7])));
    }
    zn[n] = __fadd_rn(half_s[0], half_s[1]);
}

// K1b: en[k] (numpy-pairwise, contiguous codebook row) — 4 blocks x 256.
__global__ void vq_en(const float* __restrict__ cb, float* __restrict__ en) {
    int k = blockIdx.x * 256 + threadIdx.x;
    const float* row = cb + (size_t)k * DDIM;
    float half_s[2];
    #pragma unroll
    for (int h = 0; h < 2; ++h) {
        const float* p = row + h * 128;
        float r[8];
        #pragma unroll
        for (int j = 0; j < 8; ++j) r[j] = __fmul_rn(p[j], p[j]);
        #pragma unroll
        for (int i = 8; i < 128; i += 8) {
            #pragma unroll
            for (int j = 0; j < 8; ++j)
                r[j] = __fadd_rn(r[j], __fmul_rn(p[i + j], p[i + j]));
        }
        half_s[h] = __fadd_rn(
            __fadd_rn(__fadd_rn(r[0], r[1]), __fadd_rn(r[2], r[3])),
            __fadd_rn(__fadd_rn(r[4], r[5]), __fadd_rn(r[6], r[7])));
    }
    en[k] = __fadd_rn(half_s[0], half_s[1]);
}

// K1c: transpose codebook into ET[d][k]; zero loss slot.
__global__ void vq_prep(const float* __restrict__ cb,
                        float* __restrict__ ws_f, float* __restrict__ loss_slot) {
    int k = blockIdx.x;
    int d = threadIdx.x;
    ws_f[WS_ET + d * KCODE + k] = cb[k * DDIM + d];
    if (blockIdx.x == 0 && threadIdx.x == 0) *loss_slot = 0.0f;
}

// ---------------------------------------------------------------------------
// K2: distance-GEMM + argmin, emulating the reference's f32 rounding:
//   d_k = fl( fl(zn_n + en_k) - fl(2 * (z.e_k)) ),  argmin first-index ties.
#define BM 64
#define BN 256
#define BK 16

__launch_bounds__(256, 2)
__global__ void vq_argmin(const float* __restrict__ z,
                          const float* __restrict__ ws_f,
                          int* __restrict__ idx_out) {
    __shared__ float As[BK][68];     // [dk][pos]  (+4 pad)
    __shared__ float Bs[BK][260];    // [dk][code] (+4 pad)
    __shared__ float enS[KCODE];

    const float* ET = ws_f + WS_ET;
    const float* znW = ws_f + WS_ZN;
    const float* enW = ws_f + WS_EN;

    int t  = threadIdx.x;
    int tx = t & 31;     // code group (8 codes each)
    int ty = t >> 5;     // position group (8 positions each)
    int n0 = blockIdx.x * BM;
    int b  = n0 >> 10, hw0 = n0 & 1023;
    const float* zb = z + (size_t)b * BSTRIDE + hw0;

    for (int i = t; i < KCODE; i += 256) enS[i] = enW[i];

    float znr[8];
    #pragma unroll
    for (int j = 0; j < 8; ++j) znr[j] = znW[n0 + ty * 8 + j];

    float m1[8];
    int   i1[8];
    #pragma unroll
    for (int j = 0; j < 8; ++j) { m1[j] = 1e30f; i1[j] = 0; }

    for (int kc = 0; kc < KCODE; kc += BN) {
        float acc[8][8];
        #pragma unroll
        for (int j = 0; j < 8; ++j)
            #pragma unroll
            for (int c = 0; c < 8; ++c) acc[j][c] = 0.0f;

        for (int d0 = 0; d0 < DDIM; d0 += BK) {
            __syncthreads();
            {   // stage A: 16x64 floats
                int dk = t >> 4, p4 = (t & 15) << 2;
                *reinterpret_cast<float4*>(&As[dk][p4]) =
                    *reinterpret_cast<const float4*>(zb + (size_t)(d0 + dk) * HW + p4);
            }
            #pragma unroll
            for (int i = 0; i < 4; ++i) {   // stage B: 16x256 floats
                int q = t + i * 256;
                int dk = q >> 6, k4 = (q & 63) << 2;
                *reinterpret_cast<float4*>(&Bs[dk][k4]) =
                    *reinterpret_cast<const float4*>(ET + (size_t)(d0 + dk) * KCODE + kc + k4);
            }
            __syncthreads();

            #pragma unroll
            for (int dk = 0; dk < BK; ++dk) {
                float4 a0 = *reinterpret_cast<const float4*>(&As[dk][ty * 8]);
                float4 a1 = *reinterpret_cast<const float4*>(&As[dk][ty * 8 + 4]);
                float4 b0 = *reinterpret_cast<const float4*>(&Bs[dk][tx * 8]);
                float4 b1 = *reinterpret_cast<const float4*>(&Bs[dk][tx * 8 + 4]);
                float a[8] = {a0.x, a0.y, a0.z, a0.w, a1.x, a1.y, a1.z, a1.w};
                float bb[8] = {b0.x, b0.y, b0.z, b0.w, b1.x, b1.y, b1.z, b1.w};
                #pragma unroll
                for (int j = 0; j < 8; ++j)
                    #pragma unroll
                    for (int c = 0; c < 8; ++c)
                        acc[j][c] = fmaf(a[j], bb[c], acc[j][c]);
            }
        }

        // fold chunk: d = fl(fl(zn+en) - fl(2*dot)); strict < keeps first index
        #pragma unroll
        for (int c = 0; c < 8; ++c) {
            int k = kc + tx * 8 + c;
            float ek = enS[k];
            #pragma unroll
            for (int j = 0; j < 8; ++j) {
                float t1 = __fadd_rn(znr[j], ek);
                float d  = __fsub_rn(t1, __fmul_rn(2.0f, acc[j][c]));
                if (d < m1[j]) { m1[j] = d; i1[j] = k; }
            }
        }
    }

    // cross-lane argmin over the 32 tx lanes (smaller index wins ties)
    #pragma unroll
    for (int j = 0; j < 8; ++j) {
        float a1 = m1[j];
        int   ii = i1[j];
        #pragma unroll
        for (int off = 1; off < 32; off <<= 1) {
            float o1 = __shfl_xor(a1, off, 32);
            int   oi = __shfl_xor(ii, off, 32);
            if (o1 < a1 || (o1 == a1 && oi < ii)) { a1 = o1; ii = oi; }
        }
        if (tx == 0) idx_out[n0 + ty * 8 + j] = ii;
    }
}

// ---------------------------------------------------------------------------
// K3: gather zq, transpose to (B,D,H,W), indices as float, loss accumulate.
__global__ void vq_gather(const float* __restrict__ z,
                          const float* __restrict__ cb,
                          const int* __restrict__ idx_ws,
                          float* __restrict__ out,
                          float* __restrict__ loss) {
    int n = blockIdx.x * 256 + threadIdx.x;
    int b = n >> 10, hw = n & 1023;
    int k = idx_ws[n];
    const float* e  = cb + (size_t)k * DDIM;
    const float* zp = z + (size_t)b * BSTRIDE + hw;
    float* op = out + (size_t)b * BSTRIDE + hw;
    float s = 0.0f;
    #pragma unroll 4
    for (int d = 0; d < DDIM; ++d) {
        float ev = e[d];
        float zv = zp[(size_t)d * HW];
        op[(size_t)d * HW] = ev;
        float df = ev - zv;
        s = fmaf(df, df, s);
    }
    out[OUT0_SIZE + n] = (float)k;

    #pragma unroll
    for (int off = 32; off > 0; off >>= 1) s += __shfl_down(s, off);
    __shared__ float red[4];
    int lane = threadIdx.x & 63, w = threadIdx.x >> 6;
    if (lane == 0) red[w] = s;
    __syncthreads();
    if (threadIdx.x == 0) {
        float tot = (red[0] + red[1] + red[2] + red[3]) * (2.0f / 8388608.0f);
        atomicAdd(loss, tot);
    }
}

// ---------------------------------------------------------------------------
extern "C" void kernel_launch(void* const* d_in, const int* in_sizes, int n_in,
                              void* d_out, int out_size, void* d_ws, size_t ws_size,
                              hipStream_t stream) {
    const float* z  = (const float*)d_in[0];
    const float* cb = (const float*)d_in[1];
    float* out  = (float*)d_out;
    float* ws_f = (float*)d_ws;
    int*   idx  = (int*)d_ws + WS_IDX;
    float* loss = out + OUT0_SIZE + OUT1_SIZE;

    vq_zn<<<NPOS / 256, 256, 0, stream>>>(z, ws_f + WS_ZN);
    vq_en<<<KCODE / 256, 256, 0, stream>>>(cb, ws_f + WS_EN);
    vq_prep<<<KCODE, 256, 0, stream>>>(cb, ws_f, loss);
    vq_argmin<<<NPOS / BM, 256, 0, stream>>>(z, ws_f, idx);
    vq_gather<<<NPOS / 256, 256, 0, stream>>>(z, cb, idx, out, loss);
}

// Round 4
// 353.434 us; speedup vs baseline: 1.0353x; 1.0353x over previous
//
#include <hip/hip_runtime.h>

// Problem constants
#define NPOS 32768          // B*H*W = 32*32*32
#define DDIM 256
#define KCODE 1024
#define HW 1024             // H*W
#define BSTRIDE (256*1024)  // D*H*W per batch element
#define OUT0_SIZE 8388608   // B*D*H*W
#define OUT1_SIZE 32768

// ws layout (4-byte units):
//  [0 .. 262143]        ET    : transposed codebook [d][k]    (float)
//  [262144 .. 294911]   zn    : ||z_n||^2 numpy-pairwise f32  (float, 32768)
//  [294912 .. 295935]   en    : ||e_k||^2 numpy-pairwise f32  (float, 1024)
//  [295936 .. 361471]   packed: (f32bits(d)<<32)|k per pos    (u64, 32768)
#define WS_ET     0
#define WS_ZN     262144
#define WS_EN     294912
#define WS_PACKED 295936   // 8-byte aligned (295936*4 % 8 == 0)

// ---------------------------------------------------------------------------
// numpy pairwise_sum emulation (n=256 -> two 128-blocks of 8 accumulators).
// __fadd_rn/__fmul_rn: IEEE f32 RTE, no contraction -> bitwise == numpy CPU.

// K1a: zn[n] for all positions + init packed[n] = +inf key + zero loss slot.
__global__ void vq_zn(const float* __restrict__ z, float* __restrict__ zn,
                      unsigned long long* __restrict__ packed,
                      float* __restrict__ loss_slot) {
    int n = blockIdx.x * 256 + threadIdx.x;
    int b = n >> 10, hw = n & 1023;
    const float* zp = z + (size_t)b * BSTRIDE + hw;
    float half_s[2];
    #pragma unroll
    for (int h = 0; h < 2; ++h) {
        const float* p = zp + (size_t)(h * 128) * HW;
        float r[8];
        #pragma unroll
        for (int j = 0; j < 8; ++j) {
            float v = p[(size_t)j * HW];
            r[j] = __fmul_rn(v, v);
        }
        #pragma unroll
        for (int i = 8; i < 128; i += 8) {
            #pragma unroll
            for (int j = 0; j < 8; ++j) {
                float v = p[(size_t)(i + j) * HW];
                r[j] = __fadd_rn(r[j], __fmul_rn(v, v));
            }
        }
        half_s[h] = __fadd_rn(
            __fadd_rn(__fadd_rn(r[0], r[1]), __fadd_rn(r[2], r[3])),
            __fadd_rn(__fadd_rn(r[4], r[5]), __fadd_rn(r[6], r[7])));
    }
    zn[n] = __fadd_rn(half_s[0], half_s[1]);
    packed[n] = 0xFFFFFFFFFFFFFFFFull;
    if (n == 0) *loss_slot = 0.0f;
}

// K1b: en[k] (numpy-pairwise, contiguous codebook row).
__global__ void vq_en(const float* __restrict__ cb, float* __restrict__ en) {
    int k = blockIdx.x * 256 + threadIdx.x;
    const float* row = cb + (size_t)k * DDIM;
    float half_s[2];
    #pragma unroll
    for (int h = 0; h < 2; ++h) {
        const float* p = row + h * 128;
        float r[8];
        #pragma unroll
        for (int j = 0; j < 8; ++j) r[j] = __fmul_rn(p[j], p[j]);
        #pragma unroll
        for (int i = 8; i < 128; i += 8) {
            #pragma unroll
            for (int j = 0; j < 8; ++j)
                r[j] = __fadd_rn(r[j], __fmul_rn(p[i + j], p[i + j]));
        }
        half_s[h] = __fadd_rn(
            __fadd_rn(__fadd_rn(r[0], r[1]), __fadd_rn(r[2], r[3])),
            __fadd_rn(__fadd_rn(r[4], r[5]), __fadd_rn(r[6], r[7])));
    }
    en[k] = __fadd_rn(half_s[0], half_s[1]);
}

// K1c: LDS-tiled transpose cb(1024x256) -> ET(256x1024). 64x64 tiles,
// coalesced loads AND stores. grid 16*4 = 64 blocks x 256 threads.
__global__ void vq_trans(const float* __restrict__ cb, float* __restrict__ et) {
    __shared__ float tile[64][65];
    int k0 = (blockIdx.x & 15) * 64;
    int d0 = (blockIdx.x >> 4) * 64;
    int t = threadIdx.x;
    #pragma unroll
    for (int p = 0; p < 4; ++p) {
        int r  = p * 16 + (t >> 4);
        int c4 = (t & 15) * 4;
        float4 v = *reinterpret_cast<const float4*>(
            cb + (size_t)(k0 + r) * DDIM + d0 + c4);
        tile[r][c4] = v.x; tile[r][c4+1] = v.y;
        tile[r][c4+2] = v.z; tile[r][c4+3] = v.w;
    }
    __syncthreads();
    #pragma unroll
    for (int s = 0; s < 16; ++s) {
        int dd = s * 4 + (t >> 6);
        int kk = t & 63;
        et[(size_t)(d0 + dd) * KCODE + k0 + kk] = tile[kk][dd];
    }
}

// ---------------------------------------------------------------------------
// K2: code-split distance-GEMM + argmin. Each block: 64 positions x 256 codes
// (one quarter of the codebook), full D. Per-(n,k) arithmetic is a sequential
// fmaf chain over d=0..255 then fl(fl(zn+en)-fl(2*dot)) — BIT-IDENTICAL to
// the verified round-3 kernel. Cross-block merge: atomicMin on
// (f32bits(d)<<32)|k  (d>0 always -> bits monotone; ties -> smaller k, which
// is exactly np.argmin first-index semantics).
// B tile stored skewed: code k at Bs[dk][k + (k>>3)] -> lane tx reads float4
// at 9*tx: banks 9*tx mod 32 all-distinct (9 coprime 32) -> conflict-free.
#define BM 64
#define BN 256
#define BK 16
#define BSKEW(k) ((k) + ((k) >> 3))   // max 255+31=286 -> row len 288

__launch_bounds__(256, 4)
__global__ void vq_argmin(const float* __restrict__ z,
                          const float* __restrict__ ws_f,
                          unsigned long long* __restrict__ packed) {
    __shared__ float As[BK][64];     // [dk][pos] (unpadded; reads broadcast)
    __shared__ float Bs[BK][288];    // [dk][skewed code]

    const float* ET  = ws_f + WS_ET;
    const float* znW = ws_f + WS_ZN;
    const float* enW = ws_f + WS_EN;

    int t  = threadIdx.x;
    int tx = t & 31;                 // code group (8 codes each)
    int ty = t >> 5;                 // position group (8 positions each)
    int bc = blockIdx.x & 3;         // code-range quarter
    int bm = blockIdx.x >> 2;
    int kc = bc * BN;
    int n0 = bm * BM;
    int b  = n0 >> 10, hw0 = n0 & 1023;
    const float* zb = z + (size_t)b * BSTRIDE + hw0;

    float znr[8];
    #pragma unroll
    for (int j = 0; j < 8; ++j) znr[j] = znW[n0 + ty * 8 + j];

    float acc[8][8];
    #pragma unroll
    for (int j = 0; j < 8; ++j)
        #pragma unroll
        for (int c = 0; c < 8; ++c) acc[j][c] = 0.0f;

    for (int d0 = 0; d0 < DDIM; d0 += BK) {
        __syncthreads();
        {   // stage A: 16x64 floats, 1 float4/thread
            int dk = t >> 4, p4 = (t & 15) << 2;
            float4 v = *reinterpret_cast<const float4*>(
                zb + (size_t)(d0 + dk) * HW + p4);
            As[dk][p4] = v.x; As[dk][p4+1] = v.y;
            As[dk][p4+2] = v.z; As[dk][p4+3] = v.w;
        }
        #pragma unroll
        for (int i = 0; i < 4; ++i) {   // stage B: 16x256 floats, skewed
            int q = t + i * 256;
            int dk = q >> 6, m = q & 63;          // codes 4m..4m+3
            float4 v = *reinterpret_cast<const float4*>(
                ET + (size_t)(d0 + dk) * KCODE + kc + 4 * m);
            int ph = BSKEW(4 * m);                // 4m + (m>>1), contiguous x4
            *reinterpret_cast<float4*>(&Bs[dk][ph]) = v;
        }
        __syncthreads();

        #pragma unroll
        for (int dk = 0; dk < BK; ++dk) {
            float4 a0 = *reinterpret_cast<const float4*>(&As[dk][ty * 8]);
            float4 a1 = *reinterpret_cast<const float4*>(&As[dk][ty * 8 + 4]);
            float4 b0 = *reinterpret_cast<const float4*>(&Bs[dk][9 * tx]);
            float4 b1 = *reinterpret_cast<const float4*>(&Bs[dk][9 * tx + 4]);
            float a[8]  = {a0.x, a0.y, a0.z, a0.w, a1.x, a1.y, a1.z, a1.w};
            float bb[8] = {b0.x, b0.y, b0.z, b0.w, b1.x, b1.y, b1.z, b1.w};
            #pragma unroll
            for (int j = 0; j < 8; ++j)
                #pragma unroll
                for (int c = 0; c < 8; ++c)
                    acc[j][c] = fmaf(a[j], bb[c], acc[j][c]);
        }
    }

    // epilogue: d = fl(fl(zn+en) - fl(2*dot)); strict < keeps first index
    float m1[8];
    int   i1[8];
    #pragma unroll
    for (int j = 0; j < 8; ++j) { m1[j] = 1e30f; i1[j] = 0; }
    #pragma unroll
    for (int c = 0; c < 8; ++c) {
        int k = kc + tx * 8 + c;
        float ek = enW[k];
        #pragma unroll
        for (int j = 0; j < 8; ++j) {
            float t1 = __fadd_rn(znr[j], ek);
            float d  = __fsub_rn(t1, __fmul_rn(2.0f, acc[j][c]));
            if (d < m1[j]) { m1[j] = d; i1[j] = k; }
        }
    }

    // cross-lane argmin over the 32 tx lanes (smaller index wins ties)
    #pragma unroll
    for (int j = 0; j < 8; ++j) {
        float a1 = m1[j];
        int   ii = i1[j];
        #pragma unroll
        for (int off = 1; off < 32; off <<= 1) {
            float o1 = __shfl_xor(a1, off, 32);
            int   oi = __shfl_xor(ii, off, 32);
            if (o1 < a1 || (o1 == a1 && oi < ii)) { a1 = o1; ii = oi; }
        }
        if (tx == 0) {
            unsigned long long key =
                ((unsigned long long)__float_as_uint(a1) << 32) |
                (unsigned long long)(unsigned)ii;
            atomicMin(&packed[n0 + ty * 8 + j], key);
        }
    }
}

// ---------------------------------------------------------------------------
// K3: final index extract + gather zq, transpose to (B,D,H,W), indices as
// float, loss = 2*mean((zq-zp)^2) accumulate.
__global__ void vq_gather(const float* __restrict__ z,
                          const float* __restrict__ cb,
                          const unsigned long long* __restrict__ packed,
                          float* __restrict__ out,
                          float* __restrict__ loss) {
    int n = blockIdx.x * 256 + threadIdx.x;
    int b = n >> 10, hw = n & 1023;
    int k = (int)(unsigned)(packed[n] & 0xFFFFFFFFull);
    const float* e  = cb + (size_t)k * DDIM;
    const float* zp = z + (size_t)b * BSTRIDE + hw;
    float* op = out + (size_t)b * BSTRIDE + hw;
    float s = 0.0f;
    #pragma unroll 4
    for (int d = 0; d < DDIM; ++d) {
        float ev = e[d];
        float zv = zp[(size_t)d * HW];
        op[(size_t)d * HW] = ev;
        float df = ev - zv;
        s = fmaf(df, df, s);
    }
    out[OUT0_SIZE + n] = (float)k;

    #pragma unroll
    for (int off = 32; off > 0; off >>= 1) s += __shfl_down(s, off);
    __shared__ float red[4];
    int lane = threadIdx.x & 63, w = threadIdx.x >> 6;
    if (lane == 0) red[w] = s;
    __syncthreads();
    if (threadIdx.x == 0) {
        float tot = (red[0] + red[1] + red[2] + red[3]) * (2.0f / 8388608.0f);
        atomicAdd(loss, tot);
    }
}

// ---------------------------------------------------------------------------
extern "C" void kernel_launch(void* const* d_in, const int* in_sizes, int n_in,
                              void* d_out, int out_size, void* d_ws, size_t ws_size,
                              hipStream_t stream) {
    const float* z  = (const float*)d_in[0];
    const float* cb = (const float*)d_in[1];
    float* out  = (float*)d_out;
    float* ws_f = (float*)d_ws;
    unsigned long long* packed =
        (unsigned long long*)(ws_f + WS_PACKED);
    float* loss = out + OUT0_SIZE + OUT1_SIZE;

    vq_zn<<<NPOS / 256, 256, 0, stream>>>(z, ws_f + WS_ZN, packed, loss);
    vq_en<<<KCODE / 256, 256, 0, stream>>>(cb, ws_f + WS_EN);
    vq_trans<<<64, 256, 0, stream>>>(cb, ws_f + WS_ET);
    vq_argmin<<<(NPOS / BM) * (KCODE / BN), 256, 0, stream>>>(z, ws_f, packed);
    vq_gather<<<NPOS / 256, 256, 0, stream>>>(z, cb, packed, out, loss);
}